// Round 11
// baseline (216.139 us; speedup 1.0000x reference)
//
#include <hip/hip_runtime.h>
#include <cstddef>

#define BSZ   1024
#define TT    128
#define LAB   64
#define DEMO  16
#define HID   32
#define FF    4

// sigmoid(pre) with pre' = -log2(e)*pre folded into weights: rcp(1+exp2(pre'))
// tanh(y) with y' = 2*log2(e)*y folded into weights: 1 - 2*rcp(exp2(y')+1)
__device__ __forceinline__ float sig_s(float p) {
    return __builtin_amdgcn_rcpf(1.0f + __builtin_amdgcn_exp2f(p));
}
__device__ __forceinline__ float tanh_s(float y) {
    return fmaf(-2.0f, __builtin_amdgcn_rcpf(__builtin_amdgcn_exp2f(y) + 1.0f), 1.0f);
}

// ---------------- Kernel A: xp[b][t][l] = lab_b[l] + dot(x[b,t,:], lab_W[l,:]) ----------------
// 1024 blocks x 128 threads (thread = one t). Weights via wave-uniform loads
// (compiler scalarizes to s_load, K$ pipe) — no LDS, VALU-bound.
__global__ __launch_bounds__(128)
void proj_gemm(const float* __restrict__ x,
               const float* __restrict__ lab_W,
               const float* __restrict__ lab_b,
               float* __restrict__ xp)
{
    const int b = blockIdx.x;
    const int t = threadIdx.x;             // 0..127

    // x row (64 floats) into registers
    float xr[LAB];
    const float4* xr4 = reinterpret_cast<const float4*>(x + ((size_t)b * TT + t) * LAB);
    #pragma unroll
    for (int k = 0; k < 16; ++k) {
        float4 v = xr4[k];
        xr[4*k] = v.x; xr[4*k+1] = v.y; xr[4*k+2] = v.z; xr[4*k+3] = v.w;
    }

    float* xpb = xp + ((size_t)b * TT + t) * LAB;   // [b][t][*]: thread-contiguous row
    #pragma unroll 2
    for (int l = 0; l < LAB; l += 4) {
        float4 o;
        float* op = reinterpret_cast<float*>(&o);
        #pragma unroll
        for (int q = 0; q < 4; ++q) {
            const float4* w4 = reinterpret_cast<const float4*>(lab_W + (l + q) * LAB); // uniform -> s_load
            float a0 = 0.f, a1 = 0.f, a2 = 0.f, a3 = 0.f;
            #pragma unroll
            for (int k = 0; k < 16; ++k) {
                float4 w = w4[k];
                a0 = fmaf(w.x, xr[4*k + 0], a0);
                a1 = fmaf(w.y, xr[4*k + 1], a1);
                a2 = fmaf(w.z, xr[4*k + 2], a2);
                a3 = fmaf(w.w, xr[4*k + 3], a3);
            }
            op[q] = lab_b[l + q] + ((a0 + a1) + (a2 + a3));   // lab_b uniform -> s_load
        }
        *reinterpret_cast<float4*>(xpb + l) = o;   // full-line coverage per thread
    }
}

// ---------------- Kernel B: serial GRU over xp[b][t][l] ----------------
// Per step: one coalesced global_load_dword (lane=l), 8-deep static prefetch ring.
__global__ __launch_bounds__(64, 1)
void gru_kernel(const float* __restrict__ xp,
                const float* __restrict__ stat,
                const float* __restrict__ demo_W,
                const float* __restrict__ demo_b,
                const float* __restrict__ Wih,
                const float* __restrict__ bih,
                const float* __restrict__ Whh,
                const float* __restrict__ bhh,
                const float* __restrict__ out_W,
                const float* __restrict__ out_b,
                float* __restrict__ out)
{
    const int b = blockIdx.x;
    const int l = threadIdx.x;   // one lab-chain per lane; block = 1 wave

    __shared__ float cat[HID + LAB * FF];

    const float S1 = -1.442695041f;   // -log2(e): r,z gates
    const float S2 =  2.885390082f;   // 2*log2(e): n gate

    float whh[48];
    #pragma unroll
    for (int k = 0; k < 48; k += 4) {
        float4 v = *reinterpret_cast<const float4*>(Whh + l * 48 + k);
        whh[k] = v.x; whh[k+1] = v.y; whh[k+2] = v.z; whh[k+3] = v.w;
    }
    float wih[12], bihv[12], bhhv[12];
    #pragma unroll
    for (int k = 0; k < 12; k += 4) {
        float4 a = *reinterpret_cast<const float4*>(Wih + l * 12 + k);
        float4 c = *reinterpret_cast<const float4*>(bih + l * 12 + k);
        float4 d = *reinterpret_cast<const float4*>(bhh + l * 12 + k);
        wih[k] = a.x; wih[k+1] = a.y; wih[k+2] = a.z; wih[k+3] = a.w;
        bihv[k] = c.x; bihv[k+1] = c.y; bihv[k+2] = c.z; bihv[k+3] = c.w;
        bhhv[k] = d.x; bhhv[k+1] = d.y; bhhv[k+2] = d.z; bhhv[k+3] = d.w;
    }
    float bc[8];
    #pragma unroll
    for (int g = 0; g < 8; ++g) {
        bc[g]  = S1 * (bihv[g] + bhhv[g]);
        wih[g] *= S1;
        #pragma unroll
        for (int k = 0; k < 4; ++k) whh[g*4 + k] *= S1;
    }
    #pragma unroll
    for (int g = 8; g < 12; ++g) {
        wih[g]  *= S2;
        bihv[g] *= S2;
        bhhv[g] *= S2;
        #pragma unroll
        for (int k = 0; k < 4; ++k) whh[g*4 + k] *= S2;
    }

    float h0 = 0.f, h1 = 0.f, h2 = 0.f, h3 = 0.f;

    // coalesced xt stream: xp[b][t][l], lane = l; 8-deep prefetch ring
    const float* xq = xp + (size_t)b * TT * LAB + l;
    float cur[8], nxt[8];
    #pragma unroll
    for (int j = 0; j < 8; ++j) cur[j] = xq[(size_t)j * LAB];

    #pragma unroll 1
    for (int tb = 0; tb < TT / 8; ++tb) {
        if (tb + 1 < TT / 8) {
            #pragma unroll
            for (int j = 0; j < 8; ++j)
                nxt[j] = xq[(size_t)((tb + 1) * 8 + j) * LAB];   // in flight across 8 steps
        }

        #pragma unroll
        for (int j = 0; j < 8; ++j) {
            const float xt = cur[j];

            float pre[8];
            #pragma unroll
            for (int g = 0; g < 8; ++g) {
                float acc = fmaf(xt, wih[g], bc[g]);
                acc = fmaf(h0, whh[g*4 + 0], acc);
                acc = fmaf(h1, whh[g*4 + 1], acc);
                acc = fmaf(h2, whh[g*4 + 2], acc);
                acc = fmaf(h3, whh[g*4 + 3], acc);
                pre[g] = acc;
            }
            const float r0 = sig_s(pre[0]);
            const float r1 = sig_s(pre[1]);
            const float r2 = sig_s(pre[2]);
            const float r3 = sig_s(pre[3]);
            const float z0 = sig_s(pre[4]);
            const float z1 = sig_s(pre[5]);
            const float z2 = sig_s(pre[6]);
            const float z3 = sig_s(pre[7]);

            float ghn[4], gin[4];
            #pragma unroll
            for (int i = 0; i < 4; ++i) {
                const int g = 8 + i;
                float acc = bhhv[g];
                acc = fmaf(h0, whh[g*4 + 0], acc);
                acc = fmaf(h1, whh[g*4 + 1], acc);
                acc = fmaf(h2, whh[g*4 + 2], acc);
                acc = fmaf(h3, whh[g*4 + 3], acc);
                ghn[i] = acc;
                gin[i] = fmaf(xt, wih[g], bihv[g]);
            }
            const float n0 = tanh_s(fmaf(r0, ghn[0], gin[0]));
            const float n1 = tanh_s(fmaf(r1, ghn[1], gin[1]));
            const float n2 = tanh_s(fmaf(r2, ghn[2], gin[2]));
            const float n3 = tanh_s(fmaf(r3, ghn[3], gin[3]));

            h0 = fmaf(z0, h0 - n0, n0);
            h1 = fmaf(z1, h1 - n1, n1);
            h2 = fmaf(z2, h2 - n2, n2);
            h3 = fmaf(z3, h3 - n3, n3);
        }

        #pragma unroll
        for (int j = 0; j < 8; ++j) cur[j] = nxt[j];
    }

    // ---- epilogue ----
    cat[HID + l*4 + 0] = h0;
    cat[HID + l*4 + 1] = h1;
    cat[HID + l*4 + 2] = h2;
    cat[HID + l*4 + 3] = h3;
    if (l < HID) {
        float acc = demo_b[l];
        const float* sr = stat + (size_t)b * DEMO;
        const float* dwr = demo_W + l * DEMO;
        #pragma unroll
        for (int d = 0; d < DEMO; ++d)
            acc = fmaf(sr[d], dwr[d], acc);
        cat[l] = acc;
    }
    __syncthreads();

    if (l < HID) {
        float acc = out_b[l];
        const float* wrow = out_W + l * (HID + LAB * FF);
        #pragma unroll
        for (int i = 0; i < HID + LAB * FF; i += 4) {
            float4 wv = *reinterpret_cast<const float4*>(wrow + i);
            acc = fmaf(cat[i + 0], wv.x, acc);
            acc = fmaf(cat[i + 1], wv.y, acc);
            acc = fmaf(cat[i + 2], wv.z, acc);
            acc = fmaf(cat[i + 3], wv.w, acc);
        }
        out[(size_t)b * HID + l] = acc;
    }
}

extern "C" void kernel_launch(void* const* d_in, const int* in_sizes, int n_in,
                              void* d_out, int out_size, void* d_ws, size_t ws_size,
                              hipStream_t stream) {
    const float* x      = (const float*)d_in[0];
    const float* stat   = (const float*)d_in[1];
    const float* demo_W = (const float*)d_in[2];
    const float* demo_b = (const float*)d_in[3];
    const float* lab_W  = (const float*)d_in[4];
    const float* lab_b  = (const float*)d_in[5];
    const float* Wih    = (const float*)d_in[6];
    const float* bih    = (const float*)d_in[7];
    const float* Whh    = (const float*)d_in[8];
    const float* bhh    = (const float*)d_in[9];
    const float* out_W  = (const float*)d_in[10];
    const float* out_b  = (const float*)d_in[11];
    float* out = (float*)d_out;

    float* xp = (float*)d_ws;   // [BSZ][TT][LAB] f32 = 33.55 MB

    hipLaunchKernelGGL(proj_gemm, dim3(BSZ), dim3(128), 0, stream,
                       x, lab_W, lab_b, xp);
    hipLaunchKernelGGL(gru_kernel, dim3(BSZ), dim3(LAB), 0, stream,
                       xp, stat, demo_W, demo_b, Wih, bih, Whh, bhh, out_W, out_b, out);
}

// Round 12
// 161.337 us; speedup vs baseline: 1.3397x; 1.3397x over previous
//
#include <hip/hip_runtime.h>
#include <cstddef>

#define BSZ   1024
#define TT    128
#define LAB   64
#define DEMO  16
#define HID   32
#define FF    4
#define CHUNK 32
#define NCHUNK (TT / CHUNK)

// sigmoid(pre) with pre' = -log2(e)*pre folded into weights: rcp(1+exp2(pre'))
// tanh(y) with y' = 2*log2(e)*y folded into weights: 1 - 2*rcp(exp2(y')+1)
__device__ __forceinline__ float sig_s(float p) {
    return __builtin_amdgcn_rcpf(1.0f + __builtin_amdgcn_exp2f(p));
}
__device__ __forceinline__ float tanh_s(float y) {
    return fmaf(-2.0f, __builtin_amdgcn_rcpf(__builtin_amdgcn_exp2f(y) + 1.0f), 1.0f);
}

// Keep a computed value VGPR-resident: the asm "produces" w, so the compiler
// cannot re-derive it by reloading from memory inside the loop.
#define PIN(w) asm volatile("" : "+v"(w))

__global__ __launch_bounds__(64, 1)
void mcgru_fused(const float* __restrict__ x,
                 const float* __restrict__ stat,
                 const float* __restrict__ demo_W,
                 const float* __restrict__ demo_b,
                 const float* __restrict__ lab_W,
                 const float* __restrict__ lab_b,
                 const float* __restrict__ Wih,
                 const float* __restrict__ bih,
                 const float* __restrict__ Whh,
                 const float* __restrict__ bhh,
                 const float* __restrict__ out_W,
                 const float* __restrict__ out_b,
                 float* __restrict__ out)
{
    const int b = blockIdx.x;
    const int l = threadIdx.x;   // one lab-chain per lane; block = 1 wave

    __shared__ float xs[CHUNK * LAB];        // 8 KB staged x rows
    __shared__ float cat[HID + LAB * FF];

    const float S1 = -1.442695041f;   // -log2(e): r,z gates
    const float S2 =  2.885390082f;   // 2*log2(e): n gate

    // ---- per-lane (per-lab) weights into VGPRs ----
    float wl[LAB];                        // lab_W row l (projection)
    #pragma unroll
    for (int k = 0; k < LAB; k += 4) {
        float4 v = *reinterpret_cast<const float4*>(lab_W + l * LAB + k);
        wl[k] = v.x; wl[k+1] = v.y; wl[k+2] = v.z; wl[k+3] = v.w;
    }
    float whh[48];
    #pragma unroll
    for (int k = 0; k < 48; k += 4) {
        float4 v = *reinterpret_cast<const float4*>(Whh + l * 48 + k);
        whh[k] = v.x; whh[k+1] = v.y; whh[k+2] = v.z; whh[k+3] = v.w;
    }
    float wih[12], bihv[12], bhhv[12];
    #pragma unroll
    for (int k = 0; k < 12; k += 4) {
        float4 a = *reinterpret_cast<const float4*>(Wih + l * 12 + k);
        float4 c = *reinterpret_cast<const float4*>(bih + l * 12 + k);
        float4 d = *reinterpret_cast<const float4*>(bhh + l * 12 + k);
        wih[k] = a.x; wih[k+1] = a.y; wih[k+2] = a.z; wih[k+3] = a.w;
        bihv[k] = c.x; bihv[k+1] = c.y; bihv[k+2] = c.z; bihv[k+3] = c.w;
        bhhv[k] = d.x; bhhv[k+1] = d.y; bhhv[k+2] = d.z; bhhv[k+3] = d.w;
    }
    float bc[8];
    #pragma unroll
    for (int g = 0; g < 8; ++g) {
        bc[g]  = S1 * (bihv[g] + bhhv[g]);
        wih[g] *= S1;
        #pragma unroll
        for (int k = 0; k < 4; ++k) whh[g*4 + k] *= S1;
    }
    #pragma unroll
    for (int g = 8; g < 12; ++g) {
        wih[g]  *= S2;
        bihv[g] *= S2;
        bhhv[g] *= S2;
        #pragma unroll
        for (int k = 0; k < 4; ++k) whh[g*4 + k] *= S2;
    }
    float lb = lab_b[l];

    // ---- pin the full working set (~141 floats) in VGPRs: forbids per-step reloads ----
    #pragma unroll
    for (int k = 0; k < LAB; ++k) PIN(wl[k]);
    #pragma unroll
    for (int k = 0; k < 48; ++k) PIN(whh[k]);
    #pragma unroll
    for (int k = 0; k < 12; ++k) PIN(wih[k]);
    #pragma unroll
    for (int k = 0; k < 8; ++k) PIN(bc[k]);
    #pragma unroll
    for (int k = 8; k < 12; ++k) { PIN(bihv[k]); PIN(bhhv[k]); }
    PIN(lb);

    float h0 = 0.f, h1 = 0.f, h2 = 0.f, h3 = 0.f;

    const float* xrow = x + (size_t)b * TT * LAB;

    #pragma unroll 1
    for (int c = 0; c < NCHUNK; ++c) {
        // ---- stage this chunk (8 KB): transient regs -> LDS, no long-lived array ----
        {
            const float4* src = reinterpret_cast<const float4*>(xrow + c * CHUNK * LAB);
            float4 st[8];
            #pragma unroll
            for (int i = 0; i < 8; ++i) st[i] = src[i * 64 + l];
            #pragma unroll
            for (int i = 0; i < 8; ++i)
                *reinterpret_cast<float4*>(&xs[(i * 64 + l) * 4]) = st[i];
        }
        __syncthreads();

        // ---- 32 steps: inline projection (broadcast LDS reads) + gate math ----
        #pragma unroll 2
        for (int t = 0; t < CHUNK; ++t) {
            const float4* row = reinterpret_cast<const float4*>(&xs[t * LAB]); // uniform -> broadcast
            float a0 = 0.f, a1 = 0.f, a2 = 0.f, a3 = 0.f;
            #pragma unroll
            for (int k = 0; k < LAB / 4; ++k) {
                float4 v = row[k];
                a0 = fmaf(v.x, wl[4*k + 0], a0);
                a1 = fmaf(v.y, wl[4*k + 1], a1);
                a2 = fmaf(v.z, wl[4*k + 2], a2);
                a3 = fmaf(v.w, wl[4*k + 3], a3);
            }
            const float xt = lb + ((a0 + a1) + (a2 + a3));

            float pre[8];
            #pragma unroll
            for (int g = 0; g < 8; ++g) {
                float acc = fmaf(xt, wih[g], bc[g]);
                acc = fmaf(h0, whh[g*4 + 0], acc);
                acc = fmaf(h1, whh[g*4 + 1], acc);
                acc = fmaf(h2, whh[g*4 + 2], acc);
                acc = fmaf(h3, whh[g*4 + 3], acc);
                pre[g] = acc;
            }
            const float r0 = sig_s(pre[0]);
            const float r1 = sig_s(pre[1]);
            const float r2 = sig_s(pre[2]);
            const float r3 = sig_s(pre[3]);
            const float z0 = sig_s(pre[4]);
            const float z1 = sig_s(pre[5]);
            const float z2 = sig_s(pre[6]);
            const float z3 = sig_s(pre[7]);

            float ghn[4], gin[4];
            #pragma unroll
            for (int i = 0; i < 4; ++i) {
                const int g = 8 + i;
                float acc = bhhv[g];
                acc = fmaf(h0, whh[g*4 + 0], acc);
                acc = fmaf(h1, whh[g*4 + 1], acc);
                acc = fmaf(h2, whh[g*4 + 2], acc);
                acc = fmaf(h3, whh[g*4 + 3], acc);
                ghn[i] = acc;
                gin[i] = fmaf(xt, wih[g], bihv[g]);
            }
            const float n0 = tanh_s(fmaf(r0, ghn[0], gin[0]));
            const float n1 = tanh_s(fmaf(r1, ghn[1], gin[1]));
            const float n2 = tanh_s(fmaf(r2, ghn[2], gin[2]));
            const float n3 = tanh_s(fmaf(r3, ghn[3], gin[3]));

            h0 = fmaf(z0, h0 - n0, n0);
            h1 = fmaf(z1, h1 - n1, n1);
            h2 = fmaf(z2, h2 - n2, n2);
            h3 = fmaf(z3, h3 - n3, n3);
        }
        __syncthreads();   // reads of xs done before next chunk overwrites
    }

    // ---- epilogue ----
    cat[HID + l*4 + 0] = h0;
    cat[HID + l*4 + 1] = h1;
    cat[HID + l*4 + 2] = h2;
    cat[HID + l*4 + 3] = h3;
    if (l < HID) {
        float acc = demo_b[l];
        const float* sr = stat + (size_t)b * DEMO;
        const float* dwr = demo_W + l * DEMO;
        #pragma unroll
        for (int d = 0; d < DEMO; ++d)
            acc = fmaf(sr[d], dwr[d], acc);
        cat[l] = acc;
    }
    __syncthreads();

    if (l < HID) {
        float acc = out_b[l];
        const float* wrow = out_W + l * (HID + LAB * FF);
        #pragma unroll
        for (int i = 0; i < HID + LAB * FF; i += 4) {
            float4 wv = *reinterpret_cast<const float4*>(wrow + i);
            acc = fmaf(cat[i + 0], wv.x, acc);
            acc = fmaf(cat[i + 1], wv.y, acc);
            acc = fmaf(cat[i + 2], wv.z, acc);
            acc = fmaf(cat[i + 3], wv.w, acc);
        }
        out[(size_t)b * HID + l] = acc;
    }
}

extern "C" void kernel_launch(void* const* d_in, const int* in_sizes, int n_in,
                              void* d_out, int out_size, void* d_ws, size_t ws_size,
                              hipStream_t stream) {
    const float* x      = (const float*)d_in[0];
    const float* stat   = (const float*)d_in[1];
    const float* demo_W = (const float*)d_in[2];
    const float* demo_b = (const float*)d_in[3];
    const float* lab_W  = (const float*)d_in[4];
    const float* lab_b  = (const float*)d_in[5];
    const float* Wih    = (const float*)d_in[6];
    const float* bih    = (const float*)d_in[7];
    const float* Whh    = (const float*)d_in[8];
    const float* bhh    = (const float*)d_in[9];
    const float* out_W  = (const float*)d_in[10];
    const float* out_b  = (const float*)d_in[11];
    float* out = (float*)d_out;

    hipLaunchKernelGGL(mcgru_fused, dim3(BSZ), dim3(LAB), 0, stream,
                       x, stat, demo_W, demo_b, lab_W, lab_b,
                       Wih, bih, Whh, bhh, out_W, out_b, out);
}